// Round 7
// baseline (3030.281 us; speedup 1.0000x reference)
//
#include <hip/hip_runtime.h>
#include <hip/hip_fp16.h>
#include <stdint.h>

#define N_NODES 100000
#define N_EDGES 1600000
#define IN_CH 256
#define HID 128
#define K_STEPS 10
#define ALPHA 0.1f

// dst bucketing
#define BKT_BITS 9
#define BKT_SIZE 512
#define NBKT 196                         // ceil(100000/512)
#define HBLK 256                         // blocks for hist/scatter
#define EPB (N_EDGES / HBLK)             // 6250 edges per block

// src-degree histogram partitioning
#define DR 8                             // node ranges
#define DRS (N_NODES / DR)               // 12500 nodes per range
#define DC 64                            // edge chunks
#define DCE (N_EDGES / DC)               // 25000 edges per chunk

// sliced propagation
#define NSLICE 8
#define PROP_BLOCKS 2048                 // 8 slices x 256 blocks, all co-resident
#define WPS 1024                         // waves per slice (256 blocks x 4 waves)
#define NPW ((N_NODES + WPS - 1) / WPS)  // 98 nodes per wave

typedef _Float16 f16x8 __attribute__((ext_vector_type(8)));
typedef float f32x4 __attribute__((ext_vector_type(4)));

// ---------------- K1: per-block bucket histogram (dst) ----------------
static __global__ __launch_bounds__(256) void bucket_hist_kernel(const int* __restrict__ dst,
                                                                 uint32_t* __restrict__ partials) {
    __shared__ uint32_t h[NBKT];
    int b = blockIdx.x, t = threadIdx.x;
    if (t < NBKT) h[t] = 0;
    __syncthreads();
    int base = b * EPB;
    for (int i = t; i < EPB; i += 256)
        atomicAdd(&h[(unsigned)dst[base + i] >> BKT_BITS], 1u);
    __syncthreads();
    if (t < NBKT) partials[t * HBLK + b] = h[t];          // [bucket][block]
}

// ---------------- K2a: src-degree partial histograms (packed u16 in LDS) ----------------
static __global__ __launch_bounds__(256) void srcdeg_hist_kernel(const int* __restrict__ src,
                                                                 uint16_t* __restrict__ srcpart) {
    __shared__ uint32_t h[DRS / 2];                        // 25 KB, u16 pairs
    int r = blockIdx.x >> 6;                               // range 0..7
    int c = blockIdx.x & 63;                               // chunk 0..63
    int t = threadIdx.x;
    for (int i = t; i < DRS / 2; i += 256) h[i] = 0;
    __syncthreads();
    int lo = r * DRS;
    const int4* sp = (const int4*)(src + (size_t)c * DCE);
    for (int i = t; i < DCE / 4; i += 256) {
        int4 v = sp[i];
        unsigned a0 = (unsigned)(v.x - lo);
        unsigned a1 = (unsigned)(v.y - lo);
        unsigned a2 = (unsigned)(v.z - lo);
        unsigned a3 = (unsigned)(v.w - lo);
        if (a0 < DRS) atomicAdd(&h[a0 >> 1], 1u << ((a0 & 1) * 16));
        if (a1 < DRS) atomicAdd(&h[a1 >> 1], 1u << ((a1 & 1) * 16));
        if (a2 < DRS) atomicAdd(&h[a2 >> 1], 1u << ((a2 & 1) * 16));
        if (a3 < DRS) atomicAdd(&h[a3 >> 1], 1u << ((a3 & 1) * 16));
    }
    __syncthreads();
    uint32_t* pp = (uint32_t*)(srcpart + (size_t)c * N_NODES + lo);
    for (int i = t; i < DRS / 2; i += 256) pp[i] = h[i];
}

// ---------------- K2b: reduce packed partials -> inv_out (2 nodes/thread) ----------------
static __global__ void srcdeg_reduce_kernel(const uint16_t* __restrict__ srcpart,
                                            float* __restrict__ inv_out) {
    int n2 = blockIdx.x * 256 + threadIdx.x;               // pair index
    if (n2 >= N_NODES / 2) return;
    uint32_t lo = 0, hi = 0;
#pragma unroll
    for (int c = 0; c < DC; c++) {
        uint32_t u = *(const uint32_t*)&srcpart[(size_t)c * N_NODES + 2 * n2];
        lo += u & 0xffffu;
        hi += u >> 16;
    }
    inv_out[2 * n2] = lo ? rsqrtf((float)lo) : 0.f;
    inv_out[2 * n2 + 1] = hi ? rsqrtf((float)hi) : 0.f;
}

// ---------------- K3a: per-bucket totals ----------------
static __global__ __launch_bounds__(64) void bucket_totals_kernel(const uint32_t* __restrict__ partials,
                                                                  uint32_t* __restrict__ totals) {
    int k = blockIdx.x, t = threadIdx.x;
    const uint32_t* row = partials + (size_t)k * HBLK;
    uint32_t s = row[t] + row[t + 64] + row[t + 128] + row[t + 192];
#pragma unroll
    for (int o = 32; o; o >>= 1) s += __shfl_down(s, o);
    if (t == 0) totals[k] = s;
}

// ---------------- K3c: bucket bases + per-(bucket,block) cursors ----------------
static __global__ __launch_bounds__(256) void bucket_cursor_kernel(const uint32_t* __restrict__ partials,
                                                                   const uint32_t* __restrict__ totals,
                                                                   uint32_t* __restrict__ blockCursor,
                                                                   uint32_t* __restrict__ bucket_base) {
    __shared__ uint32_t sc[256];
    int k = blockIdx.x, t = threadIdx.x;
    uint32_t tk = (t < NBKT) ? totals[t] : 0;
    sc[t] = tk;
    __syncthreads();
    for (int o = 1; o < 256; o <<= 1) {
        uint32_t u = (t >= o) ? sc[t - o] : 0;
        __syncthreads();
        sc[t] += u;
        __syncthreads();
    }
    uint32_t incl_k = sc[k];
    uint32_t total_k = totals[k];
    uint32_t base = incl_k - total_k;
    if (t == 0) {
        bucket_base[k] = base;
        if (k == NBKT - 1) bucket_base[NBKT] = incl_k;
    }
    __syncthreads();
    uint32_t p = partials[(size_t)k * HBLK + t];
    sc[t] = p;
    __syncthreads();
    for (int o = 1; o < 256; o <<= 1) {
        uint32_t u = (t >= o) ? sc[t - o] : 0;
        __syncthreads();
        sc[t] += u;
        __syncthreads();
    }
    blockCursor[(size_t)k * HBLK + t] = base + sc[t] - p;
}

// ---------------- K4: scatter edges into bucket-ordered ebuf ----------------
static __global__ __launch_bounds__(256) void bucket_scatter_kernel(const int* __restrict__ src,
                                                                    const int* __restrict__ dst,
                                                                    const uint32_t* __restrict__ blockCursor,
                                                                    int2* __restrict__ ebuf) {
    __shared__ uint32_t cur[NBKT];
    int b = blockIdx.x, t = threadIdx.x;
    if (t < NBKT) cur[t] = blockCursor[(size_t)t * HBLK + b];
    __syncthreads();
    int base = b * EPB;
    for (int i = t; i < EPB; i += 256) {
        int s = src[base + i], d = dst[base + i];
        uint32_t p = atomicAdd(&cur[(unsigned)d >> BKT_BITS], 1u);
        ebuf[p] = make_int2(s, d);
    }
}

// ---------------- K5: per-bucket CSR build (row_ptr, inv_in, csr src-only) ----------------
static __global__ __launch_bounds__(256) void bucket_build_kernel(const int2* __restrict__ ebuf,
                                                                  const uint32_t* __restrict__ bucket_base,
                                                                  int* __restrict__ row_ptr,
                                                                  float* __restrict__ inv_in,
                                                                  int* __restrict__ csr) {
    __shared__ uint32_t h[BKT_SIZE];
    __shared__ uint32_t rs[BKT_SIZE];
    __shared__ uint32_t ps[256];
    int k = blockIdx.x, t = threadIdx.x;
    uint32_t b0 = bucket_base[k], b1 = bucket_base[k + 1];
    h[t] = 0; h[t + 256] = 0;
    __syncthreads();
    for (uint32_t i = b0 + t; i < b1; i += 256)
        atomicAdd(&h[ebuf[i].y & (BKT_SIZE - 1)], 1u);
    __syncthreads();
    uint32_t a = h[2 * t], bb = h[2 * t + 1];
    uint32_t pair = a + bb;
    ps[t] = pair;
    __syncthreads();
    for (int o = 1; o < 256; o <<= 1) {
        uint32_t u = (t >= o) ? ps[t - o] : 0;
        __syncthreads();
        ps[t] += u;
        __syncthreads();
    }
    uint32_t ex = ps[t] - pair;
    rs[2 * t] = ex;
    rs[2 * t + 1] = ex + a;
    int node0 = k * BKT_SIZE;
    if (node0 + 2 * t < N_NODES) {
        row_ptr[node0 + 2 * t] = (int)(b0 + ex);
        inv_in[node0 + 2 * t] = a ? rsqrtf((float)a) : 0.f;
    }
    if (node0 + 2 * t + 1 < N_NODES) {
        row_ptr[node0 + 2 * t + 1] = (int)(b0 + ex + a);
        inv_in[node0 + 2 * t + 1] = bb ? rsqrtf((float)bb) : 0.f;
    }
    if (k == NBKT - 1 && t == 0) row_ptr[N_NODES] = (int)b1;
    __syncthreads();
    for (uint32_t i = b0 + t; i < b1; i += 256) {
        int2 e = ebuf[i];
        int li = e.y & (BKT_SIZE - 1);
        uint32_t p = atomicAdd(&rs[li], 1u);
        csr[b0 + p] = e.x;
    }
}

// ---------------- W transpose: Wt[c][k] = fp16(W[k][c]) ----------------
static __global__ __launch_bounds__(256) void wtrans_kernel(const float* __restrict__ W,
                                                            _Float16* __restrict__ Wt) {
    int k = blockIdx.x * 2 + (threadIdx.x >> 7);          // grid 128 -> k 0..255
    int c = threadIdx.x & 127;
    Wt[(size_t)c * IN_CH + k] = (_Float16)W[(size_t)k * HID + c];
}

// ---------------- MFMA GEMM: t16 (SLICED) = fp16( (A@W) * inv_out ) ----------------
__device__ __forceinline__ int kswz(int row, int kb) {
    return (kb ^ ((row ^ (row >> 2)) & 3)) << 3;           // 8-half group offset
}

static __global__ __launch_bounds__(256) void mfma_gemm_kernel(const float* __restrict__ A,
                                                               const _Float16* __restrict__ Wt,
                                                               const float* __restrict__ inv_out,
                                                               __half* __restrict__ t16) {
    __shared__ _Float16 As[128][32];     // 8 KB, k-major, swizzled groups
    __shared__ _Float16 Bs[128][32];     // 8 KB, [col][k]
    __shared__ __half  Cs[128][HID];     // 32 KB
    __shared__ float   io[128];
    int tid = threadIdx.x;
    int brow = blockIdx.x * 128;
    if (tid < 128) {
        int r = brow + tid;
        io[tid] = (r < N_NODES) ? inv_out[r] : 0.f;
    }
    int wave = tid >> 6, lane = tid & 63;
    int wm = wave >> 1, wn = wave & 1;
    int l15 = lane & 15, l4 = lane >> 4;

    f32x4 acc[4][4] = {};
    int srow = tid >> 1;
    int sko = (tid & 1) * 16;

    for (int k0 = 0; k0 < IN_CH; k0 += 32) {
        {
            float4 f[4];
            int gr = brow + srow;
            if (gr < N_NODES) {
                const float4* ap = (const float4*)&A[(size_t)gr * IN_CH + k0 + sko];
                f[0] = ap[0]; f[1] = ap[1]; f[2] = ap[2]; f[3] = ap[3];
            } else {
                f[0] = f[1] = f[2] = f[3] = make_float4(0.f, 0.f, 0.f, 0.f);
            }
#pragma unroll
            for (int g = 0; g < 2; g++) {
                _Float16 hh[8];
                float* fp = (float*)&f[2 * g];
#pragma unroll
                for (int q = 0; q < 8; q++) hh[q] = (_Float16)fp[q];
                int kb = (sko >> 3) + g;
                *(uint4*)&As[srow][kswz(srow, kb)] = *(uint4*)hh;
            }
        }
        {
            const uint4* wp = (const uint4*)&Wt[(size_t)srow * IN_CH + k0 + sko];
            uint4 u0 = wp[0], u1 = wp[1];
            int kb = sko >> 3;
            *(uint4*)&Bs[srow][kswz(srow, kb)] = u0;
            *(uint4*)&Bs[srow][kswz(srow, kb + 1)] = u1;
        }
        __syncthreads();
        f16x8 af[4], bf[4];
#pragma unroll
        for (int mt = 0; mt < 4; mt++) {
            int row = wm * 64 + mt * 16 + l15;
            af[mt] = *(f16x8*)&As[row][kswz(row, l4)];
        }
#pragma unroll
        for (int nt = 0; nt < 4; nt++) {
            int col = wn * 64 + nt * 16 + l15;
            bf[nt] = *(f16x8*)&Bs[col][kswz(col, l4)];
        }
#pragma unroll
        for (int mt = 0; mt < 4; mt++)
#pragma unroll
            for (int nt = 0; nt < 4; nt++)
                acc[mt][nt] = __builtin_amdgcn_mfma_f32_16x16x32_f16(af[mt], bf[nt], acc[mt][nt], 0, 0, 0);
        __syncthreads();
    }
#pragma unroll
    for (int mt = 0; mt < 4; mt++) {
#pragma unroll
        for (int nt = 0; nt < 4; nt++) {
#pragma unroll
            for (int r = 0; r < 4; r++) {
                int row = wm * 64 + mt * 16 + l4 * 4 + r;
                int col = wn * 64 + nt * 16 + l15;
                Cs[row][col] = __float2half(acc[mt][nt][r] * io[row]);
            }
        }
    }
    __syncthreads();
    {
        int row = tid >> 1;
        int h64 = tid & 1;                // which 64-col half
        int gr = brow + row;
        if (gr < N_NODES) {
#pragma unroll
            for (int g = 0; g < 4; g++) {
                int si = h64 * 4 + g;     // slice = col/16
                uint4* sp = (uint4*)&Cs[row][h64 * 64 + g * 16];
                uint4* dp = (uint4*)(t16 + ((size_t)si * N_NODES + gr) * 16);
                dp[0] = sp[0];
                dp[1] = sp[1];
            }
        }
    }
}

// ---------------- Sliced propagation ----------------
// g layout: [slice][node][16] fp16 (32 B rows). Block -> slice = blockIdx&7 (XCD
// round-robin affinity heuristic; correctness doesn't depend on it). Wave handles
// ~98 consecutive nodes; 16 edge slots x 4 lanes x 8 B gathers per iteration.
// MODE 0: h = relu(inv_in*acc + bias); write h0s + g = h*inv_out
// MODE 1: h = 0.9*inv_in*acc + 0.1*h0 ; write g = h*inv_out
// MODE 2: same h; write fp32 out rows
template <int MODE>
static __global__ __launch_bounds__(256, 8) void prop_slice_kernel(const _Float16* __restrict__ gin,
                                                                   const int* __restrict__ rp,
                                                                   const int* __restrict__ cs,
                                                                   const float* __restrict__ inv_in,
                                                                   const float* __restrict__ inv_out,
                                                                   const float* __restrict__ bias,
                                                                   const _Float16* __restrict__ h0s,
                                                                   _Float16* __restrict__ gout,
                                                                   _Float16* __restrict__ h0out,
                                                                   float* __restrict__ fout) {
    int s = blockIdx.x & 7;
    int wslice = (blockIdx.x >> 3) * 4 + (threadIdx.x >> 6);   // 0..WPS-1
    int lane = threadIdx.x & 63;
    int sub = lane >> 2;           // edge slot 0..15
    int cl = lane & 3;             // col group (4 cols = 8 B)
    const uint2* gsl = (const uint2*)(gin + (size_t)s * N_NODES * 16);
    const uint64_t* h0p = (const uint64_t*)(h0s + (size_t)s * N_NODES * 16);
    uint64_t* gop = (uint64_t*)(gout + (size_t)s * N_NODES * 16);
    uint64_t* h0op = (uint64_t*)(h0out + (size_t)s * N_NODES * 16);

    int n0 = wslice * NPW;
    int n1 = n0 + NPW;
    if (n1 > N_NODES) n1 = N_NODES;
    for (int wid = n0; wid < n1; ++wid) {
        int rs = rp[wid], re = rp[wid + 1];
        float a0 = 0.f, a1 = 0.f, a2 = 0.f, a3 = 0.f;
        for (int j = rs + sub; j < re; j += 16) {
            int idx = __builtin_nontemporal_load(cs + j);
            uint2 u = gsl[(size_t)idx * 4 + cl];              // L2-resident slice
            float2 f01 = __half22float2(*(__half2*)&u.x);
            float2 f23 = __half22float2(*(__half2*)&u.y);
            a0 += f01.x; a1 += f01.y; a2 += f23.x; a3 += f23.y;
        }
#pragma unroll
        for (int m = 4; m <= 32; m <<= 1) {
            a0 += __shfl_xor(a0, m);
            a1 += __shfl_xor(a1, m);
            a2 += __shfl_xor(a2, m);
            a3 += __shfl_xor(a3, m);
        }
        if (lane < 4) {
            int c0 = s * 16 + cl * 4;
            if (MODE == 0) {
                float ii = inv_in[wid], io = inv_out[wid];
                float4 bb = *(const float4*)&bias[c0];
                float h0v = fmaxf(a0 * ii + bb.x, 0.f);
                float h1v = fmaxf(a1 * ii + bb.y, 0.f);
                float h2v = fmaxf(a2 * ii + bb.z, 0.f);
                float h3v = fmaxf(a3 * ii + bb.w, 0.f);
                __half2 p01 = __floats2half2_rn(h0v, h1v);
                __half2 p23 = __floats2half2_rn(h2v, h3v);
                uint64_t uh = ((uint64_t)(*(uint32_t*)&p23) << 32) | (*(uint32_t*)&p01);
                __builtin_nontemporal_store(uh, h0op + (size_t)wid * 4 + cl);
                __half2 g01 = __floats2half2_rn(h0v * io, h1v * io);
                __half2 g23 = __floats2half2_rn(h2v * io, h3v * io);
                uint64_t ug = ((uint64_t)(*(uint32_t*)&g23) << 32) | (*(uint32_t*)&g01);
                __builtin_nontemporal_store(ug, gop + (size_t)wid * 4 + cl);
            } else {
                float ii = inv_in[wid] * (1.f - ALPHA);
                uint64_t uh = __builtin_nontemporal_load(h0p + (size_t)wid * 4 + cl);
                uint32_t hlo = (uint32_t)uh, hhi = (uint32_t)(uh >> 32);
                float2 f01 = __half22float2(*(__half2*)&hlo);
                float2 f23 = __half22float2(*(__half2*)&hhi);
                float h0v = a0 * ii + ALPHA * f01.x;
                float h1v = a1 * ii + ALPHA * f01.y;
                float h2v = a2 * ii + ALPHA * f23.x;
                float h3v = a3 * ii + ALPHA * f23.y;
                if (MODE == 1) {
                    float io = inv_out[wid];
                    __half2 g01 = __floats2half2_rn(h0v * io, h1v * io);
                    __half2 g23 = __floats2half2_rn(h2v * io, h3v * io);
                    uint64_t ug = ((uint64_t)(*(uint32_t*)&g23) << 32) | (*(uint32_t*)&g01);
                    __builtin_nontemporal_store(ug, gop + (size_t)wid * 4 + cl);
                } else {
                    *(float4*)&fout[(size_t)wid * HID + c0] = make_float4(h0v, h1v, h2v, h3v);
                }
            }
        }
    }
}

// ---------------- launch ----------------
extern "C" void kernel_launch(void* const* d_in, const int* in_sizes, int n_in,
                              void* d_out, int out_size, void* d_ws, size_t ws_size,
                              hipStream_t stream) {
    const float* features = (const float*)d_in[0];
    const float* W = (const float*)d_in[1];
    const float* b = (const float*)d_in[2];
    const int* edge_index = (const int*)d_in[3];
    const int* src = edge_index;
    const int* dst = edge_index + N_EDGES;
    float* out = (float*)d_out;

    char* ws = (char*)d_ws;
    size_t off = 0;
    auto alloc = [&](size_t bytes) -> void* {
        void* p = ws + off;
        off = (off + bytes + 255) & ~(size_t)255;
        return p;
    };
    // persistent (g buffers sliced: [8][N][16] fp16)
    int* csr = (int*)alloc(((size_t)N_EDGES + 8) * 4);                  // 6.4 MB
    _Float16* t16 = (_Float16*)alloc((size_t)NSLICE * N_NODES * 16 * 2);// 25.6 MB
    _Float16* gA  = (_Float16*)alloc((size_t)NSLICE * N_NODES * 16 * 2);// 25.6 MB
    _Float16* gB  = (_Float16*)alloc((size_t)NSLICE * N_NODES * 16 * 2);// 25.6 MB
    _Float16* h0s = (_Float16*)alloc((size_t)NSLICE * N_NODES * 16 * 2);// 25.6 MB
    float* inv_out = (float*)alloc((size_t)N_NODES * 4);
    float* inv_in = (float*)alloc((size_t)N_NODES * 4);
    int* row_ptr = (int*)alloc((size_t)(N_NODES + 1) * 4);
    _Float16* Wt = (_Float16*)alloc((size_t)HID * IN_CH * 2);           // 64 KB
    // transient, aliased over gA+gB (consumed before first prop writes them)
    char* tb = (char*)gA;
    size_t toff = 0;
    auto talloc = [&](size_t bytes) -> void* {
        void* p = tb + toff;
        toff = (toff + bytes + 255) & ~(size_t)255;
        return p;
    };
    int2* ebuf = (int2*)talloc((size_t)N_EDGES * 8);                 // 12.8 MB
    uint16_t* srcpart = (uint16_t*)talloc((size_t)DC * N_NODES * 2); // 12.8 MB
    uint32_t* partials = (uint32_t*)talloc((size_t)NBKT * HBLK * 4);
    uint32_t* blockCursor = (uint32_t*)talloc((size_t)NBKT * HBLK * 4);
    uint32_t* totals = (uint32_t*)talloc(NBKT * 4);
    uint32_t* bucket_base = (uint32_t*)talloc((NBKT + 1) * 4);

    bucket_hist_kernel<<<HBLK, 256, 0, stream>>>(dst, partials);
    srcdeg_hist_kernel<<<DR * DC, 256, 0, stream>>>(src, srcpart);
    srcdeg_reduce_kernel<<<(N_NODES / 2 + 255) / 256, 256, 0, stream>>>(srcpart, inv_out);
    bucket_totals_kernel<<<NBKT, 64, 0, stream>>>(partials, totals);
    bucket_cursor_kernel<<<NBKT, 256, 0, stream>>>(partials, totals, blockCursor, bucket_base);
    bucket_scatter_kernel<<<HBLK, 256, 0, stream>>>(src, dst, blockCursor, ebuf);
    bucket_build_kernel<<<NBKT, 256, 0, stream>>>(ebuf, bucket_base, row_ptr, inv_in, csr);

    wtrans_kernel<<<128, 256, 0, stream>>>(W, Wt);
    mfma_gemm_kernel<<<(N_NODES + 127) / 128, 256, 0, stream>>>(features, Wt, inv_out, (__half*)t16);

    // GraphConv epilogue: h0s + g0 (into gA)
    prop_slice_kernel<0><<<PROP_BLOCKS, 256, 0, stream>>>(t16, row_ptr, csr, inv_in, inv_out, b,
                                                          nullptr, gA, h0s, nullptr);
    // APPNP steps 0..8 (fp16 sliced ping-pong), step 9 writes fp32 out
    const _Float16* cur = gA;
    for (int t = 0; t < K_STEPS - 1; t++) {
        _Float16* nxt = (t & 1) ? gA : gB;
        prop_slice_kernel<1><<<PROP_BLOCKS, 256, 0, stream>>>(cur, row_ptr, csr, inv_in, inv_out,
                                                              nullptr, h0s, nxt, nullptr, nullptr);
        cur = nxt;
    }
    prop_slice_kernel<2><<<PROP_BLOCKS, 256, 0, stream>>>(cur, row_ptr, csr, inv_in, inv_out,
                                                          nullptr, h0s, nullptr, nullptr, out);
}

// Round 9
// 840.332 us; speedup vs baseline: 3.6061x; 3.6061x over previous
//
#include <hip/hip_runtime.h>
#include <hip/hip_fp16.h>
#include <stdint.h>

#define N_NODES 100000
#define N_EDGES 1600000
#define IN_CH 256
#define HID 128
#define K_STEPS 10
#define ALPHA 0.1f

// dst bucketing
#define BKT_BITS 9
#define BKT_SIZE 512
#define NBKT 196                         // ceil(100000/512)
#define HBLK 256                         // blocks for hist/scatter
#define EPB (N_EDGES / HBLK)             // 6250 edges per block

// src-degree histogram partitioning
#define DR 8                             // node ranges
#define DRS (N_NODES / DR)               // 12500 nodes per range
#define DC 64                            // edge chunks
#define DCE (N_EDGES / DC)               // 25000 edges per chunk

typedef _Float16 f16x8 __attribute__((ext_vector_type(8)));
typedef float f32x4 __attribute__((ext_vector_type(4)));
typedef unsigned int u32x4 __attribute__((ext_vector_type(4)));

// ---------------- K1: per-block bucket histogram (dst) ----------------
static __global__ __launch_bounds__(256) void bucket_hist_kernel(const int* __restrict__ dst,
                                                                 uint32_t* __restrict__ partials) {
    __shared__ uint32_t h[NBKT];
    int b = blockIdx.x, t = threadIdx.x;
    if (t < NBKT) h[t] = 0;
    __syncthreads();
    int base = b * EPB;
    for (int i = t; i < EPB; i += 256)
        atomicAdd(&h[(unsigned)dst[base + i] >> BKT_BITS], 1u);
    __syncthreads();
    if (t < NBKT) partials[t * HBLK + b] = h[t];          // [bucket][block]
}

// ---------------- K2a: src-degree partial histograms (packed u16 in LDS) ----------------
static __global__ __launch_bounds__(256) void srcdeg_hist_kernel(const int* __restrict__ src,
                                                                 uint16_t* __restrict__ srcpart) {
    __shared__ uint32_t h[DRS / 2];                        // 25 KB, u16 pairs
    int r = blockIdx.x >> 6;                               // range 0..7
    int c = blockIdx.x & 63;                               // chunk 0..63
    int t = threadIdx.x;
    for (int i = t; i < DRS / 2; i += 256) h[i] = 0;
    __syncthreads();
    int lo = r * DRS;
    const int4* sp = (const int4*)(src + (size_t)c * DCE);
    for (int i = t; i < DCE / 4; i += 256) {
        int4 v = sp[i];
        unsigned a0 = (unsigned)(v.x - lo);
        unsigned a1 = (unsigned)(v.y - lo);
        unsigned a2 = (unsigned)(v.z - lo);
        unsigned a3 = (unsigned)(v.w - lo);
        if (a0 < DRS) atomicAdd(&h[a0 >> 1], 1u << ((a0 & 1) * 16));
        if (a1 < DRS) atomicAdd(&h[a1 >> 1], 1u << ((a1 & 1) * 16));
        if (a2 < DRS) atomicAdd(&h[a2 >> 1], 1u << ((a2 & 1) * 16));
        if (a3 < DRS) atomicAdd(&h[a3 >> 1], 1u << ((a3 & 1) * 16));
    }
    __syncthreads();
    uint32_t* pp = (uint32_t*)(srcpart + (size_t)c * N_NODES + lo);
    for (int i = t; i < DRS / 2; i += 256) pp[i] = h[i];
}

// ---------------- K2b: reduce packed partials -> inv_out (2 nodes/thread) ----------------
static __global__ void srcdeg_reduce_kernel(const uint16_t* __restrict__ srcpart,
                                            float* __restrict__ inv_out) {
    int n2 = blockIdx.x * 256 + threadIdx.x;               // pair index
    if (n2 >= N_NODES / 2) return;
    uint32_t lo = 0, hi = 0;
#pragma unroll
    for (int c = 0; c < DC; c++) {
        uint32_t u = *(const uint32_t*)&srcpart[(size_t)c * N_NODES + 2 * n2];
        lo += u & 0xffffu;
        hi += u >> 16;
    }
    inv_out[2 * n2] = lo ? rsqrtf((float)lo) : 0.f;
    inv_out[2 * n2 + 1] = hi ? rsqrtf((float)hi) : 0.f;
}

// ---------------- K3a: per-bucket totals ----------------
static __global__ __launch_bounds__(64) void bucket_totals_kernel(const uint32_t* __restrict__ partials,
                                                                  uint32_t* __restrict__ totals) {
    int k = blockIdx.x, t = threadIdx.x;
    const uint32_t* row = partials + (size_t)k * HBLK;
    uint32_t s = row[t] + row[t + 64] + row[t + 128] + row[t + 192];
#pragma unroll
    for (int o = 32; o; o >>= 1) s += __shfl_down(s, o);
    if (t == 0) totals[k] = s;
}

// ---------------- K3c: bucket bases + per-(bucket,block) cursors ----------------
static __global__ __launch_bounds__(256) void bucket_cursor_kernel(const uint32_t* __restrict__ partials,
                                                                   const uint32_t* __restrict__ totals,
                                                                   uint32_t* __restrict__ blockCursor,
                                                                   uint32_t* __restrict__ bucket_base) {
    __shared__ uint32_t sc[256];
    int k = blockIdx.x, t = threadIdx.x;
    uint32_t tk = (t < NBKT) ? totals[t] : 0;
    sc[t] = tk;
    __syncthreads();
    for (int o = 1; o < 256; o <<= 1) {
        uint32_t u = (t >= o) ? sc[t - o] : 0;
        __syncthreads();
        sc[t] += u;
        __syncthreads();
    }
    uint32_t incl_k = sc[k];
    uint32_t total_k = totals[k];
    uint32_t base = incl_k - total_k;
    if (t == 0) {
        bucket_base[k] = base;
        if (k == NBKT - 1) bucket_base[NBKT] = incl_k;
    }
    __syncthreads();
    uint32_t p = partials[(size_t)k * HBLK + t];
    sc[t] = p;
    __syncthreads();
    for (int o = 1; o < 256; o <<= 1) {
        uint32_t u = (t >= o) ? sc[t - o] : 0;
        __syncthreads();
        sc[t] += u;
        __syncthreads();
    }
    blockCursor[(size_t)k * HBLK + t] = base + sc[t] - p;
}

// ---------------- K4: scatter edges into bucket-ordered ebuf ----------------
static __global__ __launch_bounds__(256) void bucket_scatter_kernel(const int* __restrict__ src,
                                                                    const int* __restrict__ dst,
                                                                    const uint32_t* __restrict__ blockCursor,
                                                                    int2* __restrict__ ebuf) {
    __shared__ uint32_t cur[NBKT];
    int b = blockIdx.x, t = threadIdx.x;
    if (t < NBKT) cur[t] = blockCursor[(size_t)t * HBLK + b];
    __syncthreads();
    int base = b * EPB;
    for (int i = t; i < EPB; i += 256) {
        int s = src[base + i], d = dst[base + i];
        uint32_t p = atomicAdd(&cur[(unsigned)d >> BKT_BITS], 1u);
        ebuf[p] = make_int2(s, d);
    }
}

// ---------------- K5: per-bucket CSR build (row_ptr, inv_in, csr src-only) ----------------
static __global__ __launch_bounds__(256) void bucket_build_kernel(const int2* __restrict__ ebuf,
                                                                  const uint32_t* __restrict__ bucket_base,
                                                                  int* __restrict__ row_ptr,
                                                                  float* __restrict__ inv_in,
                                                                  int* __restrict__ csr) {
    __shared__ uint32_t h[BKT_SIZE];
    __shared__ uint32_t rs[BKT_SIZE];
    __shared__ uint32_t ps[256];
    int k = blockIdx.x, t = threadIdx.x;
    uint32_t b0 = bucket_base[k], b1 = bucket_base[k + 1];
    h[t] = 0; h[t + 256] = 0;
    __syncthreads();
    for (uint32_t i = b0 + t; i < b1; i += 256)
        atomicAdd(&h[ebuf[i].y & (BKT_SIZE - 1)], 1u);
    __syncthreads();
    uint32_t a = h[2 * t], bb = h[2 * t + 1];
    uint32_t pair = a + bb;
    ps[t] = pair;
    __syncthreads();
    for (int o = 1; o < 256; o <<= 1) {
        uint32_t u = (t >= o) ? ps[t - o] : 0;
        __syncthreads();
        ps[t] += u;
        __syncthreads();
    }
    uint32_t ex = ps[t] - pair;
    rs[2 * t] = ex;
    rs[2 * t + 1] = ex + a;
    int node0 = k * BKT_SIZE;
    if (node0 + 2 * t < N_NODES) {
        row_ptr[node0 + 2 * t] = (int)(b0 + ex);
        inv_in[node0 + 2 * t] = a ? rsqrtf((float)a) : 0.f;
    }
    if (node0 + 2 * t + 1 < N_NODES) {
        row_ptr[node0 + 2 * t + 1] = (int)(b0 + ex + a);
        inv_in[node0 + 2 * t + 1] = bb ? rsqrtf((float)bb) : 0.f;
    }
    if (k == NBKT - 1 && t == 0) row_ptr[N_NODES] = (int)b1;
    __syncthreads();
    for (uint32_t i = b0 + t; i < b1; i += 256) {
        int2 e = ebuf[i];
        int li = e.y & (BKT_SIZE - 1);
        uint32_t p = atomicAdd(&rs[li], 1u);
        csr[b0 + p] = e.x;
    }
}

// ---------------- W transpose: Wt[c][k] = fp16(W[k][c]) ----------------
static __global__ __launch_bounds__(256) void wtrans_kernel(const float* __restrict__ W,
                                                            _Float16* __restrict__ Wt) {
    int k = blockIdx.x * 2 + (threadIdx.x >> 7);          // grid 128 -> k 0..255
    int c = threadIdx.x & 127;
    Wt[(size_t)c * IN_CH + k] = (_Float16)W[(size_t)k * HID + c];
}

// ---------------- MFMA GEMM: t16[r] = fp16( (A@W)[r] * inv_out[r] ) ----------------
__device__ __forceinline__ int kswz(int row, int kb) {
    return (kb ^ ((row ^ (row >> 2)) & 3)) << 3;           // 8-half group offset
}

static __global__ __launch_bounds__(256) void mfma_gemm_kernel(const float* __restrict__ A,
                                                               const _Float16* __restrict__ Wt,
                                                               const float* __restrict__ inv_out,
                                                               __half* __restrict__ t16) {
    __shared__ _Float16 As[128][32];     // 8 KB, k-major, swizzled groups
    __shared__ _Float16 Bs[128][32];     // 8 KB, [col][k]
    __shared__ __half  Cs[128][HID];     // 32 KB
    __shared__ float   io[128];
    int tid = threadIdx.x;
    int brow = blockIdx.x * 128;
    if (tid < 128) {
        int r = brow + tid;
        io[tid] = (r < N_NODES) ? inv_out[r] : 0.f;
    }
    int wave = tid >> 6, lane = tid & 63;
    int wm = wave >> 1, wn = wave & 1;
    int l15 = lane & 15, l4 = lane >> 4;

    f32x4 acc[4][4] = {};
    int srow = tid >> 1;
    int sko = (tid & 1) * 16;

    for (int k0 = 0; k0 < IN_CH; k0 += 32) {
        {
            float4 f[4];
            int gr = brow + srow;
            if (gr < N_NODES) {
                const float4* ap = (const float4*)&A[(size_t)gr * IN_CH + k0 + sko];
                f[0] = ap[0]; f[1] = ap[1]; f[2] = ap[2]; f[3] = ap[3];
            } else {
                f[0] = f[1] = f[2] = f[3] = make_float4(0.f, 0.f, 0.f, 0.f);
            }
#pragma unroll
            for (int g = 0; g < 2; g++) {
                _Float16 hh[8];
                float* fp = (float*)&f[2 * g];
#pragma unroll
                for (int q = 0; q < 8; q++) hh[q] = (_Float16)fp[q];
                int kb = (sko >> 3) + g;
                *(uint4*)&As[srow][kswz(srow, kb)] = *(uint4*)hh;
            }
        }
        {
            const uint4* wp = (const uint4*)&Wt[(size_t)srow * IN_CH + k0 + sko];
            uint4 u0 = wp[0], u1 = wp[1];
            int kb = sko >> 3;
            *(uint4*)&Bs[srow][kswz(srow, kb)] = u0;
            *(uint4*)&Bs[srow][kswz(srow, kb + 1)] = u1;
        }
        __syncthreads();
        f16x8 af[4], bf[4];
#pragma unroll
        for (int mt = 0; mt < 4; mt++) {
            int row = wm * 64 + mt * 16 + l15;
            af[mt] = *(f16x8*)&As[row][kswz(row, l4)];
        }
#pragma unroll
        for (int nt = 0; nt < 4; nt++) {
            int col = wn * 64 + nt * 16 + l15;
            bf[nt] = *(f16x8*)&Bs[col][kswz(col, l4)];
        }
#pragma unroll
        for (int mt = 0; mt < 4; mt++)
#pragma unroll
            for (int nt = 0; nt < 4; nt++)
                acc[mt][nt] = __builtin_amdgcn_mfma_f32_16x16x32_f16(af[mt], bf[nt], acc[mt][nt], 0, 0, 0);
        __syncthreads();
    }
#pragma unroll
    for (int mt = 0; mt < 4; mt++) {
#pragma unroll
        for (int nt = 0; nt < 4; nt++) {
#pragma unroll
            for (int r = 0; r < 4; r++) {
                int row = wm * 64 + mt * 16 + l4 * 4 + r;
                int col = wn * 64 + nt * 16 + l15;
                Cs[row][col] = __float2half(acc[mt][nt][r] * io[row]);
            }
        }
    }
    __syncthreads();
    {
        int row = tid >> 1;
        int c0 = (tid & 1) * 64;
        int gr = brow + row;
        if (gr < N_NODES) {
            uint4* s = (uint4*)&Cs[row][c0];
            uint4* d = (uint4*)&t16[(size_t)gr * HID + c0];
#pragma unroll
            for (int i = 0; i < 8; i++) d[i] = s[i];
        }
    }
}

// ---------------- zero the sentinel row N in fp16 buffers ----------------
static __global__ void zero_rows_kernel(__half* a, __half* b, __half* c) {
    int t = threadIdx.x;                 // 64 threads, row = 64 u32
    ((uint32_t*)a)[(size_t)N_NODES * 64 + t] = 0;
    ((uint32_t*)b)[(size_t)N_NODES * 64 + t] = 0;
    ((uint32_t*)c)[(size_t)N_NODES * 64 + t] = 0;
}

// ---------------- Propagation, fp16 gathers (R6 structure + stream hygiene) ----------------
// Wave: 4 subgroups x 16 lanes; subgroup handles one edge; lane covers 8 cols.
// gin gathers use default (L2-cached) loads; streamed data (cs, h0h) and all
// outputs are nontemporal so gin rows keep L2 residency.
template <int MODE>
static __global__ __launch_bounds__(256) void prop16_kernel(const __half* __restrict__ gin,
                                                            const int* __restrict__ rp,
                                                            const int* __restrict__ cs,
                                                            const float* __restrict__ inv_in,
                                                            const float* __restrict__ inv_out,
                                                            const float* __restrict__ bias,
                                                            const __half* __restrict__ h0h,
                                                            __half* __restrict__ gout,
                                                            __half* __restrict__ h0out,
                                                            float* __restrict__ fout) {
    int wid = (int)((blockIdx.x * 256u + threadIdx.x) >> 6);
    if (wid >= N_NODES) return;
    int lane = threadIdx.x & 63;
    int sub = lane >> 4;
    int cl = lane & 15;
    int s = rp[wid], e = rp[wid + 1];
    const uint4* g4 = (const uint4*)gin;          // 16 uint4 per row

    float a[8] = {};
    for (int j = s; j < e; j += 8) {
        int j0 = j + sub, j1 = j0 + 4;
        int v0 = __builtin_nontemporal_load(cs + j0);
        int v1 = __builtin_nontemporal_load(cs + j1);   // csr alloc padded by 8
        int i0 = (j0 < e) ? v0 : N_NODES;
        int i1 = (j1 < e) ? v1 : N_NODES;
        uint4 u0 = g4[(size_t)i0 * 16 + cl];
        uint4 u1 = g4[(size_t)i1 * 16 + cl];
        const __half2* p0 = (const __half2*)&u0;
        const __half2* p1 = (const __half2*)&u1;
#pragma unroll
        for (int k = 0; k < 4; k++) {
            float2 f0 = __half22float2(p0[k]);
            float2 f1 = __half22float2(p1[k]);
            a[2 * k] += f0.x + f1.x;
            a[2 * k + 1] += f0.y + f1.y;
        }
    }
#pragma unroll
    for (int k = 0; k < 8; k++) {
        a[k] += __shfl_xor(a[k], 16);
        a[k] += __shfl_xor(a[k], 32);
    }
    if (sub != 0) return;
    int c0 = cl * 8;
    if (MODE == 0) {
        float ii = inv_in[wid], io = inv_out[wid];
        float4 b0 = *(const float4*)&bias[c0];
        float4 b1 = *(const float4*)&bias[c0 + 4];
        float h[8];
        h[0] = fmaxf(a[0] * ii + b0.x, 0.f);
        h[1] = fmaxf(a[1] * ii + b0.y, 0.f);
        h[2] = fmaxf(a[2] * ii + b0.z, 0.f);
        h[3] = fmaxf(a[3] * ii + b0.w, 0.f);
        h[4] = fmaxf(a[4] * ii + b1.x, 0.f);
        h[5] = fmaxf(a[5] * ii + b1.y, 0.f);
        h[6] = fmaxf(a[6] * ii + b1.z, 0.f);
        h[7] = fmaxf(a[7] * ii + b1.w, 0.f);
        __half2 hh[4], gg[4];
#pragma unroll
        for (int k = 0; k < 4; k++) {
            hh[k] = __floats2half2_rn(h[2 * k], h[2 * k + 1]);
            gg[k] = __floats2half2_rn(h[2 * k] * io, h[2 * k + 1] * io);
        }
        __builtin_nontemporal_store(*(u32x4*)hh, (u32x4*)h0out + (size_t)wid * 16 + cl);
        __builtin_nontemporal_store(*(u32x4*)gg, (u32x4*)gout + (size_t)wid * 16 + cl);
    } else {
        float ii = inv_in[wid] * (1.f - ALPHA);
        u32x4 uh = __builtin_nontemporal_load((const u32x4*)h0h + (size_t)wid * 16 + cl);
        const __half2* ph = (const __half2*)&uh;
        float h[8];
#pragma unroll
        for (int k = 0; k < 4; k++) {
            float2 f = __half22float2(ph[k]);
            h[2 * k] = a[2 * k] * ii + ALPHA * f.x;
            h[2 * k + 1] = a[2 * k + 1] * ii + ALPHA * f.y;
        }
        if (MODE == 1) {
            float io = inv_out[wid];
            __half2 gg[4];
#pragma unroll
            for (int k = 0; k < 4; k++)
                gg[k] = __floats2half2_rn(h[2 * k] * io, h[2 * k + 1] * io);
            __builtin_nontemporal_store(*(u32x4*)gg, (u32x4*)gout + (size_t)wid * 16 + cl);
        } else {
            f32x4 o0 = {h[0], h[1], h[2], h[3]};
            f32x4 o1 = {h[4], h[5], h[6], h[7]};
            __builtin_nontemporal_store(o0, (f32x4*)&fout[(size_t)wid * HID + c0]);
            __builtin_nontemporal_store(o1, (f32x4*)&fout[(size_t)wid * HID + c0 + 4]);
        }
    }
}

// ---------------- launch ----------------
extern "C" void kernel_launch(void* const* d_in, const int* in_sizes, int n_in,
                              void* d_out, int out_size, void* d_ws, size_t ws_size,
                              hipStream_t stream) {
    const float* features = (const float*)d_in[0];
    const float* W = (const float*)d_in[1];
    const float* b = (const float*)d_in[2];
    const int* edge_index = (const int*)d_in[3];
    const int* src = edge_index;
    const int* dst = edge_index + N_EDGES;
    float* out = (float*)d_out;

    char* ws = (char*)d_ws;
    size_t off = 0;
    auto alloc = [&](size_t bytes) -> void* {
        void* p = ws + off;
        off = (off + bytes + 255) & ~(size_t)255;
        return p;
    };
    // persistent
    int* csr = (int*)alloc(((size_t)N_EDGES + 8) * 4);              // 6.4 MB
    __half* t16 = (__half*)alloc((size_t)(N_NODES + 1) * HID * 2);  // 25.6 MB
    __half* gA  = (__half*)alloc((size_t)(N_NODES + 1) * HID * 2);  // 25.6 MB
    __half* gB  = (__half*)alloc((size_t)(N_NODES + 1) * HID * 2);  // 25.6 MB
    __half* h0h = (__half*)alloc((size_t)N_NODES * HID * 2);        // 25.6 MB
    float* inv_out = (float*)alloc((size_t)N_NODES * 4);
    float* inv_in = (float*)alloc((size_t)N_NODES * 4);
    int* row_ptr = (int*)alloc((size_t)(N_NODES + 1) * 4);
    _Float16* Wt = (_Float16*)alloc((size_t)HID * IN_CH * 2);       // 64 KB
    // transient, aliased over gA+gB (consumed before first prop writes them)
    char* tb = (char*)gA;
    size_t toff = 0;
    auto talloc = [&](size_t bytes) -> void* {
        void* p = tb + toff;
        toff = (toff + bytes + 255) & ~(size_t)255;
        return p;
    };
    int2* ebuf = (int2*)talloc((size_t)N_EDGES * 8);                 // 12.8 MB
    uint16_t* srcpart = (uint16_t*)talloc((size_t)DC * N_NODES * 2); // 12.8 MB
    uint32_t* partials = (uint32_t*)talloc((size_t)NBKT * HBLK * 4);
    uint32_t* blockCursor = (uint32_t*)talloc((size_t)NBKT * HBLK * 4);
    uint32_t* totals = (uint32_t*)talloc(NBKT * 4);
    uint32_t* bucket_base = (uint32_t*)talloc((NBKT + 1) * 4);

    bucket_hist_kernel<<<HBLK, 256, 0, stream>>>(dst, partials);
    srcdeg_hist_kernel<<<DR * DC, 256, 0, stream>>>(src, srcpart);
    srcdeg_reduce_kernel<<<(N_NODES / 2 + 255) / 256, 256, 0, stream>>>(srcpart, inv_out);
    bucket_totals_kernel<<<NBKT, 64, 0, stream>>>(partials, totals);
    bucket_cursor_kernel<<<NBKT, 256, 0, stream>>>(partials, totals, blockCursor, bucket_base);
    bucket_scatter_kernel<<<HBLK, 256, 0, stream>>>(src, dst, blockCursor, ebuf);
    bucket_build_kernel<<<NBKT, 256, 0, stream>>>(ebuf, bucket_base, row_ptr, inv_in, csr);

    wtrans_kernel<<<128, 256, 0, stream>>>(W, Wt);
    mfma_gemm_kernel<<<(N_NODES + 127) / 128, 256, 0, stream>>>(features, Wt, inv_out, (__half*)t16);
    zero_rows_kernel<<<1, 64, 0, stream>>>(t16, gA, gB);

    int pb = (int)(((size_t)N_NODES * 64) / 256);
    // GraphConv epilogue: h0h + g0 (into gA)
    prop16_kernel<0><<<pb, 256, 0, stream>>>(t16, row_ptr, csr, inv_in, inv_out, b, nullptr,
                                             gA, h0h, nullptr);
    // APPNP steps 0..8 (fp16 ping-pong), step 9 writes fp32 out
    const __half* cur = gA;
    for (int t = 0; t < K_STEPS - 1; t++) {
        __half* nxt = (t & 1) ? gA : gB;
        prop16_kernel<1><<<pb, 256, 0, stream>>>(cur, row_ptr, csr, inv_in, inv_out, nullptr, h0h,
                                                 nxt, nullptr, nullptr);
        cur = nxt;
    }
    prop16_kernel<2><<<pb, 256, 0, stream>>>(cur, row_ptr, csr, inv_in, inv_out, nullptr, h0h,
                                             nullptr, nullptr, out);
}

// Round 10
// 794.495 us; speedup vs baseline: 3.8141x; 1.0577x over previous
//
#include <hip/hip_runtime.h>
#include <hip/hip_fp16.h>
#include <stdint.h>

#define N_NODES 100000
#define N_EDGES 1600000
#define IN_CH 256
#define HID 128
#define K_STEPS 10
#define ALPHA 0.1f

// dst bucketing
#define BKT_BITS 9
#define BKT_SIZE 512
#define NBKT 196                         // ceil(100000/512)
#define HBLK 256                         // blocks for hist/scatter
#define EPB (N_EDGES / HBLK)             // 6250 edges per block

// src-degree histogram partitioning
#define DR 8                             // node ranges
#define DRS (N_NODES / DR)               // 12500 nodes per range
#define DC 64                            // edge chunks
#define DCE (N_EDGES / DC)               // 25000 edges per chunk

typedef _Float16 f16x8 __attribute__((ext_vector_type(8)));
typedef float f32x4 __attribute__((ext_vector_type(4)));

// ---------------- K1: per-block bucket histogram (dst) ----------------
static __global__ __launch_bounds__(256) void bucket_hist_kernel(const int* __restrict__ dst,
                                                                 uint32_t* __restrict__ partials) {
    __shared__ uint32_t h[NBKT];
    int b = blockIdx.x, t = threadIdx.x;
    if (t < NBKT) h[t] = 0;
    __syncthreads();
    int base = b * EPB;
    for (int i = t; i < EPB; i += 256)
        atomicAdd(&h[(unsigned)dst[base + i] >> BKT_BITS], 1u);
    __syncthreads();
    if (t < NBKT) partials[t * HBLK + b] = h[t];          // [bucket][block]
}

// ---------------- K2a: src-degree partial histograms (packed u16 in LDS) ----------------
static __global__ __launch_bounds__(256) void srcdeg_hist_kernel(const int* __restrict__ src,
                                                                 uint16_t* __restrict__ srcpart) {
    __shared__ uint32_t h[DRS / 2];                        // 25 KB, u16 pairs
    int r = blockIdx.x >> 6;                               // range 0..7
    int c = blockIdx.x & 63;                               // chunk 0..63
    int t = threadIdx.x;
    for (int i = t; i < DRS / 2; i += 256) h[i] = 0;
    __syncthreads();
    int lo = r * DRS;
    const int4* sp = (const int4*)(src + (size_t)c * DCE);
    for (int i = t; i < DCE / 4; i += 256) {
        int4 v = sp[i];
        unsigned a0 = (unsigned)(v.x - lo);
        unsigned a1 = (unsigned)(v.y - lo);
        unsigned a2 = (unsigned)(v.z - lo);
        unsigned a3 = (unsigned)(v.w - lo);
        if (a0 < DRS) atomicAdd(&h[a0 >> 1], 1u << ((a0 & 1) * 16));
        if (a1 < DRS) atomicAdd(&h[a1 >> 1], 1u << ((a1 & 1) * 16));
        if (a2 < DRS) atomicAdd(&h[a2 >> 1], 1u << ((a2 & 1) * 16));
        if (a3 < DRS) atomicAdd(&h[a3 >> 1], 1u << ((a3 & 1) * 16));
    }
    __syncthreads();
    uint32_t* pp = (uint32_t*)(srcpart + (size_t)c * N_NODES + lo);
    for (int i = t; i < DRS / 2; i += 256) pp[i] = h[i];
}

// ---------------- K2b: reduce packed partials -> inv_out (2 nodes/thread) ----------------
static __global__ void srcdeg_reduce_kernel(const uint16_t* __restrict__ srcpart,
                                            float* __restrict__ inv_out) {
    int n2 = blockIdx.x * 256 + threadIdx.x;               // pair index
    if (n2 >= N_NODES / 2) return;
    uint32_t lo = 0, hi = 0;
#pragma unroll
    for (int c = 0; c < DC; c++) {
        uint32_t u = *(const uint32_t*)&srcpart[(size_t)c * N_NODES + 2 * n2];
        lo += u & 0xffffu;
        hi += u >> 16;
    }
    inv_out[2 * n2] = lo ? rsqrtf((float)lo) : 0.f;
    inv_out[2 * n2 + 1] = hi ? rsqrtf((float)hi) : 0.f;
}

// ---------------- K3a: per-bucket totals ----------------
static __global__ __launch_bounds__(64) void bucket_totals_kernel(const uint32_t* __restrict__ partials,
                                                                  uint32_t* __restrict__ totals) {
    int k = blockIdx.x, t = threadIdx.x;
    const uint32_t* row = partials + (size_t)k * HBLK;
    uint32_t s = row[t] + row[t + 64] + row[t + 128] + row[t + 192];
#pragma unroll
    for (int o = 32; o; o >>= 1) s += __shfl_down(s, o);
    if (t == 0) totals[k] = s;
}

// ---------------- K3c: bucket bases + per-(bucket,block) cursors ----------------
static __global__ __launch_bounds__(256) void bucket_cursor_kernel(const uint32_t* __restrict__ partials,
                                                                   const uint32_t* __restrict__ totals,
                                                                   uint32_t* __restrict__ blockCursor,
                                                                   uint32_t* __restrict__ bucket_base) {
    __shared__ uint32_t sc[256];
    int k = blockIdx.x, t = threadIdx.x;
    uint32_t tk = (t < NBKT) ? totals[t] : 0;
    sc[t] = tk;
    __syncthreads();
    for (int o = 1; o < 256; o <<= 1) {
        uint32_t u = (t >= o) ? sc[t - o] : 0;
        __syncthreads();
        sc[t] += u;
        __syncthreads();
    }
    uint32_t incl_k = sc[k];
    uint32_t total_k = totals[k];
    uint32_t base = incl_k - total_k;
    if (t == 0) {
        bucket_base[k] = base;
        if (k == NBKT - 1) bucket_base[NBKT] = incl_k;
    }
    __syncthreads();
    uint32_t p = partials[(size_t)k * HBLK + t];
    sc[t] = p;
    __syncthreads();
    for (int o = 1; o < 256; o <<= 1) {
        uint32_t u = (t >= o) ? sc[t - o] : 0;
        __syncthreads();
        sc[t] += u;
        __syncthreads();
    }
    blockCursor[(size_t)k * HBLK + t] = base + sc[t] - p;
}

// ---------------- K4: scatter edges into bucket-ordered ebuf ----------------
static __global__ __launch_bounds__(256) void bucket_scatter_kernel(const int* __restrict__ src,
                                                                    const int* __restrict__ dst,
                                                                    const uint32_t* __restrict__ blockCursor,
                                                                    int2* __restrict__ ebuf) {
    __shared__ uint32_t cur[NBKT];
    int b = blockIdx.x, t = threadIdx.x;
    if (t < NBKT) cur[t] = blockCursor[(size_t)t * HBLK + b];
    __syncthreads();
    int base = b * EPB;
    for (int i = t; i < EPB; i += 256) {
        int s = src[base + i], d = dst[base + i];
        uint32_t p = atomicAdd(&cur[(unsigned)d >> BKT_BITS], 1u);
        ebuf[p] = make_int2(s, d);
    }
}

// ---------------- K5: per-bucket CSR build (row_ptr, inv_in, csr src-only) ----------------
static __global__ __launch_bounds__(256) void bucket_build_kernel(const int2* __restrict__ ebuf,
                                                                  const uint32_t* __restrict__ bucket_base,
                                                                  int* __restrict__ row_ptr,
                                                                  float* __restrict__ inv_in,
                                                                  int* __restrict__ csr) {
    __shared__ uint32_t h[BKT_SIZE];
    __shared__ uint32_t rs[BKT_SIZE];
    __shared__ uint32_t ps[256];
    int k = blockIdx.x, t = threadIdx.x;
    uint32_t b0 = bucket_base[k], b1 = bucket_base[k + 1];
    h[t] = 0; h[t + 256] = 0;
    __syncthreads();
    for (uint32_t i = b0 + t; i < b1; i += 256)
        atomicAdd(&h[ebuf[i].y & (BKT_SIZE - 1)], 1u);
    __syncthreads();
    uint32_t a = h[2 * t], bb = h[2 * t + 1];
    uint32_t pair = a + bb;
    ps[t] = pair;
    __syncthreads();
    for (int o = 1; o < 256; o <<= 1) {
        uint32_t u = (t >= o) ? ps[t - o] : 0;
        __syncthreads();
        ps[t] += u;
        __syncthreads();
    }
    uint32_t ex = ps[t] - pair;
    rs[2 * t] = ex;
    rs[2 * t + 1] = ex + a;
    int node0 = k * BKT_SIZE;
    if (node0 + 2 * t < N_NODES) {
        row_ptr[node0 + 2 * t] = (int)(b0 + ex);
        inv_in[node0 + 2 * t] = a ? rsqrtf((float)a) : 0.f;
    }
    if (node0 + 2 * t + 1 < N_NODES) {
        row_ptr[node0 + 2 * t + 1] = (int)(b0 + ex + a);
        inv_in[node0 + 2 * t + 1] = bb ? rsqrtf((float)bb) : 0.f;
    }
    if (k == NBKT - 1 && t == 0) row_ptr[N_NODES] = (int)b1;
    __syncthreads();
    for (uint32_t i = b0 + t; i < b1; i += 256) {
        int2 e = ebuf[i];
        int li = e.y & (BKT_SIZE - 1);
        uint32_t p = atomicAdd(&rs[li], 1u);
        csr[b0 + p] = e.x;
    }
}

// ---------------- W transpose: Wt[c][k] = fp16(W[k][c]) ----------------
static __global__ __launch_bounds__(256) void wtrans_kernel(const float* __restrict__ W,
                                                            _Float16* __restrict__ Wt) {
    int k = blockIdx.x * 2 + (threadIdx.x >> 7);          // grid 128 -> k 0..255
    int c = threadIdx.x & 127;
    Wt[(size_t)c * IN_CH + k] = (_Float16)W[(size_t)k * HID + c];
}

// ---------------- MFMA GEMM: t16[r] = fp16( (A@W)[r] * inv_out[r] ) ----------------
__device__ __forceinline__ int kswz(int row, int kb) {
    return (kb ^ ((row ^ (row >> 2)) & 3)) << 3;           // 8-half group offset
}

static __global__ __launch_bounds__(256) void mfma_gemm_kernel(const float* __restrict__ A,
                                                               const _Float16* __restrict__ Wt,
                                                               const float* __restrict__ inv_out,
                                                               __half* __restrict__ t16) {
    __shared__ _Float16 As[128][32];     // 8 KB, k-major, swizzled groups
    __shared__ _Float16 Bs[128][32];     // 8 KB, [col][k]
    __shared__ __half  Cs[128][HID];     // 32 KB
    __shared__ float   io[128];
    int tid = threadIdx.x;
    int brow = blockIdx.x * 128;
    if (tid < 128) {
        int r = brow + tid;
        io[tid] = (r < N_NODES) ? inv_out[r] : 0.f;
    }
    int wave = tid >> 6, lane = tid & 63;
    int wm = wave >> 1, wn = wave & 1;
    int l15 = lane & 15, l4 = lane >> 4;

    f32x4 acc[4][4] = {};
    int srow = tid >> 1;
    int sko = (tid & 1) * 16;

    for (int k0 = 0; k0 < IN_CH; k0 += 32) {
        {
            float4 f[4];
            int gr = brow + srow;
            if (gr < N_NODES) {
                const float4* ap = (const float4*)&A[(size_t)gr * IN_CH + k0 + sko];
                f[0] = ap[0]; f[1] = ap[1]; f[2] = ap[2]; f[3] = ap[3];
            } else {
                f[0] = f[1] = f[2] = f[3] = make_float4(0.f, 0.f, 0.f, 0.f);
            }
#pragma unroll
            for (int g = 0; g < 2; g++) {
                _Float16 hh[8];
                float* fp = (float*)&f[2 * g];
#pragma unroll
                for (int q = 0; q < 8; q++) hh[q] = (_Float16)fp[q];
                int kb = (sko >> 3) + g;
                *(uint4*)&As[srow][kswz(srow, kb)] = *(uint4*)hh;
            }
        }
        {
            const uint4* wp = (const uint4*)&Wt[(size_t)srow * IN_CH + k0 + sko];
            uint4 u0 = wp[0], u1 = wp[1];
            int kb = sko >> 3;
            *(uint4*)&Bs[srow][kswz(srow, kb)] = u0;
            *(uint4*)&Bs[srow][kswz(srow, kb + 1)] = u1;
        }
        __syncthreads();
        f16x8 af[4], bf[4];
#pragma unroll
        for (int mt = 0; mt < 4; mt++) {
            int row = wm * 64 + mt * 16 + l15;
            af[mt] = *(f16x8*)&As[row][kswz(row, l4)];
        }
#pragma unroll
        for (int nt = 0; nt < 4; nt++) {
            int col = wn * 64 + nt * 16 + l15;
            bf[nt] = *(f16x8*)&Bs[col][kswz(col, l4)];
        }
#pragma unroll
        for (int mt = 0; mt < 4; mt++)
#pragma unroll
            for (int nt = 0; nt < 4; nt++)
                acc[mt][nt] = __builtin_amdgcn_mfma_f32_16x16x32_f16(af[mt], bf[nt], acc[mt][nt], 0, 0, 0);
        __syncthreads();
    }
#pragma unroll
    for (int mt = 0; mt < 4; mt++) {
#pragma unroll
        for (int nt = 0; nt < 4; nt++) {
#pragma unroll
            for (int r = 0; r < 4; r++) {
                int row = wm * 64 + mt * 16 + l4 * 4 + r;
                int col = wn * 64 + nt * 16 + l15;
                Cs[row][col] = __float2half(acc[mt][nt][r] * io[row]);
            }
        }
    }
    __syncthreads();
    {
        int row = tid >> 1;
        int c0 = (tid & 1) * 64;
        int gr = brow + row;
        if (gr < N_NODES) {
            uint4* s = (uint4*)&Cs[row][c0];
            uint4* d = (uint4*)&t16[(size_t)gr * HID + c0];
#pragma unroll
            for (int i = 0; i < 8; i++) d[i] = s[i];
        }
    }
}

// ---------------- zero the sentinel row N in fp16 buffers ----------------
static __global__ void zero_rows_kernel(__half* a, __half* b, __half* c) {
    int t = threadIdx.x;                 // 64 threads, row = 64 u32
    ((uint32_t*)a)[(size_t)N_NODES * 64 + t] = 0;
    ((uint32_t*)b)[(size_t)N_NODES * 64 + t] = 0;
    ((uint32_t*)c)[(size_t)N_NODES * 64 + t] = 0;
}

// ---------------- Propagation, fp16 gathers (R6-exact) ----------------
// Wave: 4 subgroups x 16 lanes; subgroup handles one edge; lane covers 8 cols.
template <int MODE>
static __global__ __launch_bounds__(256) void prop16_kernel(const __half* __restrict__ gin,
                                                            const int* __restrict__ rp,
                                                            const int* __restrict__ cs,
                                                            const float* __restrict__ inv_in,
                                                            const float* __restrict__ inv_out,
                                                            const float* __restrict__ bias,
                                                            const __half* __restrict__ h0h,
                                                            __half* __restrict__ gout,
                                                            __half* __restrict__ h0out,
                                                            float* __restrict__ fout) {
    int wid = (int)((blockIdx.x * 256u + threadIdx.x) >> 6);
    if (wid >= N_NODES) return;
    int lane = threadIdx.x & 63;
    int sub = lane >> 4;
    int cl = lane & 15;
    int s = rp[wid], e = rp[wid + 1];
    const uint4* g4 = (const uint4*)gin;          // 16 uint4 per row

    float a[8] = {};
    for (int j = s; j < e; j += 8) {
        int j0 = j + sub, j1 = j0 + 4;
        int v0 = cs[j0], v1 = cs[j1];             // csr alloc padded by 8
        int i0 = (j0 < e) ? v0 : N_NODES;
        int i1 = (j1 < e) ? v1 : N_NODES;
        uint4 u0 = g4[(size_t)i0 * 16 + cl];
        uint4 u1 = g4[(size_t)i1 * 16 + cl];
        const __half2* p0 = (const __half2*)&u0;
        const __half2* p1 = (const __half2*)&u1;
#pragma unroll
        for (int k = 0; k < 4; k++) {
            float2 f0 = __half22float2(p0[k]);
            float2 f1 = __half22float2(p1[k]);
            a[2 * k] += f0.x + f1.x;
            a[2 * k + 1] += f0.y + f1.y;
        }
    }
#pragma unroll
    for (int k = 0; k < 8; k++) {
        a[k] += __shfl_xor(a[k], 16);
        a[k] += __shfl_xor(a[k], 32);
    }
    if (sub != 0) return;
    int c0 = cl * 8;
    if (MODE == 0) {
        float ii = inv_in[wid], io = inv_out[wid];
        float4 b0 = *(const float4*)&bias[c0];
        float4 b1 = *(const float4*)&bias[c0 + 4];
        float h[8];
        h[0] = fmaxf(a[0] * ii + b0.x, 0.f);
        h[1] = fmaxf(a[1] * ii + b0.y, 0.f);
        h[2] = fmaxf(a[2] * ii + b0.z, 0.f);
        h[3] = fmaxf(a[3] * ii + b0.w, 0.f);
        h[4] = fmaxf(a[4] * ii + b1.x, 0.f);
        h[5] = fmaxf(a[5] * ii + b1.y, 0.f);
        h[6] = fmaxf(a[6] * ii + b1.z, 0.f);
        h[7] = fmaxf(a[7] * ii + b1.w, 0.f);
        __half2 hh[4], gg[4];
#pragma unroll
        for (int k = 0; k < 4; k++) {
            hh[k] = __floats2half2_rn(h[2 * k], h[2 * k + 1]);
            gg[k] = __floats2half2_rn(h[2 * k] * io, h[2 * k + 1] * io);
        }
        ((uint4*)h0out)[(size_t)wid * 16 + cl] = *(uint4*)hh;
        ((uint4*)gout)[(size_t)wid * 16 + cl] = *(uint4*)gg;
    } else {
        float ii = inv_in[wid] * (1.f - ALPHA);
        uint4 uh = ((const uint4*)h0h)[(size_t)wid * 16 + cl];
        const __half2* ph = (const __half2*)&uh;
        float h[8];
#pragma unroll
        for (int k = 0; k < 4; k++) {
            float2 f = __half22float2(ph[k]);
            h[2 * k] = a[2 * k] * ii + ALPHA * f.x;
            h[2 * k + 1] = a[2 * k + 1] * ii + ALPHA * f.y;
        }
        if (MODE == 1) {
            float io = inv_out[wid];
            __half2 gg[4];
#pragma unroll
            for (int k = 0; k < 4; k++)
                gg[k] = __floats2half2_rn(h[2 * k] * io, h[2 * k + 1] * io);
            ((uint4*)gout)[(size_t)wid * 16 + cl] = *(uint4*)gg;
        } else {
            *(float4*)&fout[(size_t)wid * HID + c0] = make_float4(h[0], h[1], h[2], h[3]);
            *(float4*)&fout[(size_t)wid * HID + c0 + 4] = make_float4(h[4], h[5], h[6], h[7]);
        }
    }
}

// ---------------- launch ----------------
extern "C" void kernel_launch(void* const* d_in, const int* in_sizes, int n_in,
                              void* d_out, int out_size, void* d_ws, size_t ws_size,
                              hipStream_t stream) {
    const float* features = (const float*)d_in[0];
    const float* W = (const float*)d_in[1];
    const float* b = (const float*)d_in[2];
    const int* edge_index = (const int*)d_in[3];
    const int* src = edge_index;
    const int* dst = edge_index + N_EDGES;
    float* out = (float*)d_out;

    char* ws = (char*)d_ws;
    size_t off = 0;
    auto alloc = [&](size_t bytes) -> void* {
        void* p = ws + off;
        off = (off + bytes + 255) & ~(size_t)255;
        return p;
    };
    // persistent
    int* csr = (int*)alloc(((size_t)N_EDGES + 8) * 4);              // 6.4 MB
    __half* t16 = (__half*)alloc((size_t)(N_NODES + 1) * HID * 2);  // 25.6 MB
    __half* gA  = (__half*)alloc((size_t)(N_NODES + 1) * HID * 2);  // 25.6 MB
    __half* gB  = (__half*)alloc((size_t)(N_NODES + 1) * HID * 2);  // 25.6 MB
    __half* h0h = (__half*)alloc((size_t)N_NODES * HID * 2);        // 25.6 MB
    float* inv_out = (float*)alloc((size_t)N_NODES * 4);
    float* inv_in = (float*)alloc((size_t)N_NODES * 4);
    int* row_ptr = (int*)alloc((size_t)(N_NODES + 1) * 4);
    _Float16* Wt = (_Float16*)alloc((size_t)HID * IN_CH * 2);       // 64 KB
    // transient, aliased over gA+gB (consumed before first prop writes them)
    char* tb = (char*)gA;
    size_t toff = 0;
    auto talloc = [&](size_t bytes) -> void* {
        void* p = tb + toff;
        toff = (toff + bytes + 255) & ~(size_t)255;
        return p;
    };
    int2* ebuf = (int2*)talloc((size_t)N_EDGES * 8);                 // 12.8 MB
    uint16_t* srcpart = (uint16_t*)talloc((size_t)DC * N_NODES * 2); // 12.8 MB
    uint32_t* partials = (uint32_t*)talloc((size_t)NBKT * HBLK * 4);
    uint32_t* blockCursor = (uint32_t*)talloc((size_t)NBKT * HBLK * 4);
    uint32_t* totals = (uint32_t*)talloc(NBKT * 4);
    uint32_t* bucket_base = (uint32_t*)talloc((NBKT + 1) * 4);

    bucket_hist_kernel<<<HBLK, 256, 0, stream>>>(dst, partials);
    srcdeg_hist_kernel<<<DR * DC, 256, 0, stream>>>(src, srcpart);
    srcdeg_reduce_kernel<<<(N_NODES / 2 + 255) / 256, 256, 0, stream>>>(srcpart, inv_out);
    bucket_totals_kernel<<<NBKT, 64, 0, stream>>>(partials, totals);
    bucket_cursor_kernel<<<NBKT, 256, 0, stream>>>(partials, totals, blockCursor, bucket_base);
    bucket_scatter_kernel<<<HBLK, 256, 0, stream>>>(src, dst, blockCursor, ebuf);
    bucket_build_kernel<<<NBKT, 256, 0, stream>>>(ebuf, bucket_base, row_ptr, inv_in, csr);

    wtrans_kernel<<<128, 256, 0, stream>>>(W, Wt);
    mfma_gemm_kernel<<<(N_NODES + 127) / 128, 256, 0, stream>>>(features, Wt, inv_out, (__half*)t16);
    zero_rows_kernel<<<1, 64, 0, stream>>>(t16, gA, gB);

    int pb = (int)(((size_t)N_NODES * 64) / 256);
    // GraphConv epilogue: h0h + g0 (into gA)
    prop16_kernel<0><<<pb, 256, 0, stream>>>(t16, row_ptr, csr, inv_in, inv_out, b, nullptr,
                                             gA, h0h, nullptr);
    // APPNP steps 0..8 (fp16 ping-pong), step 9 writes fp32 out
    const __half* cur = gA;
    for (int t = 0; t < K_STEPS - 1; t++) {
        __half* nxt = (t & 1) ? gA : gB;
        prop16_kernel<1><<<pb, 256, 0, stream>>>(cur, row_ptr, csr, inv_in, inv_out, nullptr, h0h,
                                                 nxt, nullptr, nullptr);
        cur = nxt;
    }
    prop16_kernel<2><<<pb, 256, 0, stream>>>(cur, row_ptr, csr, inv_in, inv_out, nullptr, h0h,
                                             nullptr, nullptr, out);
}